// Round 5
// baseline (90.014 us; speedup 1.0000x reference)
//
#include <hip/hip_runtime.h>
#include <math.h>

#define B   8
#define S   256
#define NT  50
#define E   64
#define NTE (NT * E)
#define EPSF 1e-16f

#define NW        4                 // waves per block
#define LL_BLOCKS (B * S / 2)       // 1024 blocks; each handles rows (ih, S-1-ih)
#define IN_BLOCKS (B * NT)          // 400 blocks

__device__ __forceinline__ float softplus(float x) {
    if (x > 20.0f) return x;
    return log1pf(__expf(x));
}

__device__ __forceinline__ float wave_reduce_sum(float v) {
    #pragma unroll
    for (int off = 32; off > 0; off >>= 1)
        v += __shfl_down(v, off, 64);
    return v;  // lane 0 holds the sum
}

// ---------------------------------------------------------------------------
// Fused main kernel. Grid = LL_BLOCKS + IN_BLOCKS, 256 threads (4 waves).
//
// LL blocks: block = (b, row pair (ih, 255-ih)), i0=ih < i1=255-ih. ONE fused
// j-loop over j<i1 shares the s_ev/ej LDS reads between both rows; row-0 body
// runs under the wave-uniform guard j<i0 (no divergence). s_ev is packed
// (time, ty*NTE, ty*E) so the inner loop has no integer multiplies.
//   m[b,i,e] = sum_{j<i} emb_i*A[ty_j,ty_i,e]*exp(-emb_i*P[ty_j,ty_i,e]*emb_j*dt)*emb_j
//   ws_ll[bid] = sum over 2 rows of (valid_i ? log(sum_e softplus(...)+EPS) : 0)
// (m is NOT masked by j-validity; only the outer ll sum is — matches ref.)
//
// Integral blocks: (b,k) per block, waves split the i-loop; s_ev packs
// (dT, ty*NTE, ty*E, validity) so the loop is pure fp math + 2 loads.
//   ws_int[(b,k)] = sum_e softplus(emb_k*a_k + m_T)
// ---------------------------------------------------------------------------
__global__ __launch_bounds__(64 * NW) void main_kernel(
    const float* __restrict__ times, const int* __restrict__ types,
    const int* __restrict__ Tp,
    const float* __restrict__ emb,  const float* __restrict__ a,
    const float* __restrict__ Amat, const float* __restrict__ Pmat,
    float* __restrict__ ws_ll, float* __restrict__ ws_int)
{
    const int tid = threadIdx.x;
    const int e   = tid & 63;
    const int w   = tid >> 6;
    const int bid = blockIdx.x;
    const bool is_ll = (bid < LL_BLOCKS);
    const int b = is_ll ? (bid / (S / 2)) : ((bid - LL_BLOCKS) / NT);

    __shared__ __align__(16) float s_emb[NTE];   // 12.8 KB, lane-contiguous
    __shared__ __align__(16) float4 s_ev[S];     // packed event record
    __shared__ float  s_part[2][NW][E];
    __shared__ float  s_row[2];

    // stage emb with float4
    {
        const float4* __restrict__ emb4 = (const float4*)emb;
        float4* s4 = (float4*)s_emb;
        for (int idx = tid; idx < NTE / 4; idx += 64 * NW)
            s4[idx] = emb4[idx];
    }
    {
        const float Tf = (float)(*Tp);
        for (int j = tid; j < S; j += 64 * NW) {
            const float tj = times[b * S + j];
            const int   ty = types[b * S + j];
            float4 ev;
            if (is_ll) {
                ev = make_float4(tj, __int_as_float(ty * NTE),
                                 __int_as_float(ty * E), 0.0f);
            } else {
                ev = make_float4(Tf - tj, __int_as_float(ty * NTE),
                                 __int_as_float(ty * E),
                                 (tj >= 0.0f) ? 1.0f : 0.0f);
            }
            s_ev[j] = ev;
        }
    }
    __syncthreads();

    if (is_ll) {
        const int ih = bid % (S / 2);
        const int i0 = ih;          // shorter row
        const int i1 = S - 1 - ih;  // longer row
        const float t0   = s_ev[i0].x;
        const float t1   = s_ev[i1].x;
        const int   col0 = __float_as_int(s_ev[i0].z) + e;
        const int   col1 = __float_as_int(s_ev[i1].z) + e;
        const float negE0 = -s_emb[col0];
        const float negE1 = -s_emb[col1];

        float m0 = 0.0f, m1 = 0.0f;
        #pragma unroll 4
        for (int j = w; j < i1; j += NW) {
            const float4 ev  = s_ev[j];
            const int tyNTE  = __float_as_int(ev.y);
            const float ej   = s_emb[__float_as_int(ev.z) + e];
            // row 1 (always: j < i1)
            {
                const int base = tyNTE + col1;
                m1 = fmaf(Amat[base] * ej,
                          __expf(negE1 * Pmat[base] * ej * (t1 - ev.x)), m1);
            }
            // row 0 (wave-uniform guard)
            if (j < i0) {
                const int base = tyNTE + col0;
                m0 = fmaf(Amat[base] * ej,
                          __expf(negE0 * Pmat[base] * ej * (t0 - ev.x)), m0);
            }
        }
        s_part[0][w][e] = m0;
        s_part[1][w][e] = m1;
        __syncthreads();
        if (w < 2) {
            const int   i    = (w == 0) ? i0 : i1;
            const float t_i  = s_ev[i].x;
            const int   col  = __float_as_int(s_ev[i].z) + e;
            const float embi = s_emb[col];
            float mt = 0.0f;
            #pragma unroll
            for (int q = 0; q < NW; ++q) mt += s_part[w][q][e];
            const float sp    = softplus(fmaf(embi, mt, embi * a[col]));
            const float inten = wave_reduce_sum(sp);
            if (e == 0)
                s_row[w] = (t_i >= 0.0f) ? logf(inten + EPSF) : 0.0f;
        }
        __syncthreads();
        if (tid == 0) ws_ll[bid] = s_row[0] + s_row[1];
    } else {
        const int   k     = (bid - LL_BLOCKS) % NT;
        const int   colk  = k * E + e;
        const float embk  = s_emb[colk];
        const float negEk = -embk;

        float acc = 0.0f;
        #pragma unroll 8
        for (int i = w; i < S; i += NW) {
            const float4 ev = s_ev[i];
            const int  base = __float_as_int(ev.y) + colk;
            const float et  = s_emb[__float_as_int(ev.z) + e];
            acc = fmaf(Amat[base] * et * ev.w,
                       __expf(negEk * Pmat[base] * et * ev.x), acc);
        }
        s_part[0][w][e] = acc;
        __syncthreads();
        if (w == 0) {
            float mt = 0.0f;
            #pragma unroll
            for (int q = 0; q < NW; ++q) mt += s_part[0][q][e];
            const float sp = softplus(fmaf(embk, mt, embk * a[colk]));
            const float s  = wave_reduce_sum(sp);
            if (e == 0) ws_int[bid - LL_BLOCKS] = s;
        }
    }
}

// ---------------------------------------------------------------------------
// Finalize: one block, 4 waves. Tree-reduce ll partials + base_sum via LDS;
// per-batch min/max/intenT via one wave each (shuffle reductions).
// out = integral - ll
// ---------------------------------------------------------------------------
__global__ __launch_bounds__(256) void finalize_kernel(
    const float* __restrict__ times,
    const int* __restrict__ Tp,
    const float* __restrict__ emb, const float* __restrict__ a,
    const float* __restrict__ ws_ll, const float* __restrict__ ws_int,
    float* __restrict__ out)
{
    const int t    = threadIdx.x;
    const int lane = t & 63;
    const int w    = t >> 6;
    const float Tf = (float)(*Tp);

    float llp = 0.0f;
    for (int idx = t; idx < LL_BLOCKS; idx += 256) llp += ws_ll[idx];
    float bs = 0.0f;
    for (int idx = t; idx < NTE; idx += 256) bs += softplus(emb[idx] * a[idx]);

    __shared__ float red[256], red2[256];
    red[t] = llp; red2[t] = bs;

    __shared__ float s_first[B], s_last[B], s_iT[B], s_any[B];
    for (int b = w; b < B; b += 4) {
        float mn = 1e30f, mx = -1e30f;
        #pragma unroll
        for (int q = 0; q < S / 64; ++q) {
            const float tv = times[b * S + q * 64 + lane];
            const bool valid = (tv >= 0.0f);
            mn = fminf(mn, valid ? tv : 1e30f);
            mx = fmaxf(mx, valid ? tv : -1e30f);
        }
        float iv = (lane < NT) ? ws_int[b * NT + lane] : 0.0f;
        #pragma unroll
        for (int off = 32; off > 0; off >>= 1) {
            mn = fminf(mn, __shfl_down(mn, off, 64));
            mx = fmaxf(mx, __shfl_down(mx, off, 64));
            iv += __shfl_down(iv, off, 64);
        }
        if (lane == 0) {
            const bool any_valid = (mn < 1e29f);
            s_any[b]   = any_valid ? 1.0f : 0.0f;
            s_first[b] = any_valid ? mn : 0.0f;
            s_last[b]  = any_valid ? mx : 0.0f;
            s_iT[b]    = iv;
        }
    }
    __syncthreads();

    for (int off = 128; off > 0; off >>= 1) {
        if (t < off) { red[t] += red[t + off]; red2[t] += red2[t + off]; }
        __syncthreads();
    }

    if (t == 0) {
        const float base_sum = red2[0];
        float integral = 0.0f;
        #pragma unroll
        for (int b = 0; b < B; ++b) {
            integral += (s_any[b] > 0.5f)
                ? s_iT[b] * (Tf - s_last[b]) + base_sum * s_first[b]
                : base_sum * Tf;
        }
        out[0] = integral - red[0];
    }
}

extern "C" void kernel_launch(void* const* d_in, const int* in_sizes, int n_in,
                              void* d_out, int out_size, void* d_ws, size_t ws_size,
                              hipStream_t stream) {
    const float* times = (const float*)d_in[0];
    const int*   types = (const int*)d_in[1];
    const int*   Tp    = (const int*)d_in[2];
    const float* emb   = (const float*)d_in[3];
    const float* a     = (const float*)d_in[4];
    const float* Amat  = (const float*)d_in[5];
    const float* Pmat  = (const float*)d_in[6];

    float* ws     = (float*)d_ws;
    float* ws_ll  = ws;                  // [0, 1024)
    float* ws_int = ws + LL_BLOCKS;      // [1024, 1424)
    float* out    = (float*)d_out;

    main_kernel<<<LL_BLOCKS + IN_BLOCKS, 64 * NW, 0, stream>>>(
        times, types, Tp, emb, a, Amat, Pmat, ws_ll, ws_int);
    finalize_kernel<<<1, 256, 0, stream>>>(times, Tp, emb, a, ws_ll, ws_int, out);
}